// Round 6
// baseline (549.243 us; speedup 1.0000x reference)
//
#include <hip/hip_runtime.h>
#include <cstdint>

#define NNUM 100
#define NCAT 100
#define CATC 100
#define NCOND 128
#define GN_EPS 1e-5f

typedef __attribute__((ext_vector_type(8))) short bfrag8;   // 8 bf16 = 4 VGPRs
typedef __attribute__((ext_vector_type(4))) float accf4;    // 4 fp32 acc

__device__ __forceinline__ float sigmoidf_(float x) { return 1.0f / (1.0f + __expf(-x)); }

__device__ __forceinline__ ushort f2bf(float f) {
    uint32_t u = __builtin_bit_cast(uint32_t, f);
    u += 0x7fffu + ((u >> 16) & 1u);   // round-to-nearest-even
    return (ushort)(u >> 16);
}
__device__ __forceinline__ float bf2f(ushort h) {
    return __builtin_bit_cast(float, (uint32_t)h << 16);
}

// ---------------------------------------------------------------------------
// prep_all: ONE launch for all precomputation.
//  blocks 0..99   (g): E[g][cat][o] = (emb_row(g,cat)*gn_w[g]) @ W_cat[g]
//                      via 4-term split-bf16 MFMA (~fp32 accurate).
//                      MFMA A-tile padding rows double as free matvecs:
//                        row 100 = gn_w  -> Q[g][o] = sum_i gn_w*W
//                        row 101 = gn_b  -> P[g][o] = sum_i gn_b*W (+b_cat)
//                      Row stats S[r]=(rs,-mean*rs) computed in a pre-pass.
//                      W converted in-block to chunked frag-layout LDS
//                      (round-2 verified layout), no global Wf.
//  blocks 100..149: transpose W_num/b_num (100x128 -> 128x100) into Wt/Bt.
// LDS = 64 KB (A hi/lo full + W hi/lo chunk).
// ---------------------------------------------------------------------------
__global__ __launch_bounds__(256)
void prep_all(const float* __restrict__ emb_table,
              const float* __restrict__ W_cat,
              const float* __restrict__ gn_w,
              const float* __restrict__ gn_b,
              const float* __restrict__ b_cat,
              const float* __restrict__ W_num,
              const float* __restrict__ b_num,
              float* __restrict__ E, float* __restrict__ Q, float* __restrict__ P,
              float2* __restrict__ S,
              float* __restrict__ Wt, float* __restrict__ Bt)
{
    const int tid  = threadIdx.x;

    if (blockIdx.x >= NCAT) {
        // ---- transpose_wn path ----
        int idx = (blockIdx.x - NCAT) * 256 + tid;
        if (idx < NCOND * NNUM) {
            int c = idx / NNUM, j = idx - c * NNUM;
            Wt[idx] = W_num[j * NCOND + c];
            Bt[idx] = b_num[j * NCOND + c];
        }
        return;
    }

    const int g    = blockIdx.x;
    const int lane = tid & 63;
    const int w    = tid >> 6;        // wave 0..3

    __shared__ __align__(16) ushort Ahi[128 * 64];   // [m][k_chunk] swizzled, 16 KB
    __shared__ __align__(16) ushort Alo[128 * 64];   // 16 KB
    __shared__ __align__(16) ushort Wc[2][8192];     // W hi/lo chunk frag planes, 32 KB

    // ---- stats pre-pass: wave w does rows w, w+4, ..., w+96 ----
    const float2* emb2 = (const float2*)emb_table;
    #pragma unroll 5
    for (int i = 0; i < 25; ++i) {
        int m = w + 4 * i;
        float2 v = emb2[(size_t)(g * CATC + m) * 64 + lane];
        float s  = v.x + v.y;
        float ss = v.x * v.x + v.y * v.y;
        #pragma unroll
        for (int off = 32; off > 0; off >>= 1) {
            s  += __shfl_xor(s,  off, 64);
            ss += __shfl_xor(ss, off, 64);
        }
        float mean = s * 0.0078125f;
        float var  = fmaf(-mean, mean, ss * 0.0078125f);
        float rs   = rsqrtf(var + GN_EPS);
        if (lane == 0) S[g * CATC + m] = make_float2(rs, -mean * rs);
    }

    accf4 acc[2][8];
    #pragma unroll
    for (int gi = 0; gi < 2; ++gi)
        #pragma unroll
        for (int t = 0; t < 8; ++t)
            acc[gi][t] = (accf4){0.f, 0.f, 0.f, 0.f};

    const float* Wg = W_cat + ((size_t)g << 14);
    const int half = lane >> 5;
    const int l5   = lane & 31;

    for (int ch = 0; ch < 2; ++ch) {
        __syncthreads();   // protect W LDS reuse across chunks

        // ---- stage W chunk (k rows ch*64..ch*64+63) -> split-bf16 frag LDS ----
        #pragma unroll 2
        for (int it = 0; it < 8; ++it) {
            int lin4 = it * 256 + tid;               // 0..2047 float4s in chunk
            int kl   = lin4 >> 5;                    // k_local 0..63
            int c4   = (lin4 & 31) << 2;
            float4 v = ((const float4*)Wg)[(ch << 11) + lin4];
            int kk = kl >> 5, j = kl & 7, lq = ((kl >> 3) & 3) << 4;
            float vv[4] = {v.x, v.y, v.z, v.w};
            #pragma unroll
            for (int e = 0; e < 4; ++e) {
                int c  = c4 + e;
                int t  = c >> 4;
                int lf = (c & 15) | lq;
                int o  = (((t * 2 + kk) * 64 + lf) << 3) + j;
                ushort h = f2bf(vv[e]);
                Wc[0][o] = h;
                Wc[1][o] = f2bf(vv[e] - bf2f(h));
            }
        }

        // ---- stage A chunk (wave-local rows 32w..32w+31, k = ch*64 + 2*l5..) ----
        float2 gw2 = ((const float2*)(gn_w + g * NCOND + ch * 64))[l5];
        float2 gb2 = ((const float2*)(gn_b + g * NCOND + ch * 64))[l5];
        #pragma unroll 8
        for (int it = 0; it < 16; ++it) {
            int r = it * 2 + half;
            int m = w * 32 + r;
            float2 x;
            if (m < CATC) {
                float2 v = emb2[(size_t)(g * CATC + m) * 64 + ch * 32 + l5];
                x.x = v.x * gw2.x; x.y = v.y * gw2.y;
            } else if (m == CATC)     x = gw2;        // -> Q
            else if (m == CATC + 1)   x = gb2;        // -> P part
            else                      x = make_float2(0.f, 0.f);
            ushort h0 = f2bf(x.x), h1 = f2bf(x.y);
            uint32_t hp = (uint32_t)h0 | ((uint32_t)h1 << 16);
            uint32_t lp = (uint32_t)f2bf(x.x - bf2f(h0)) | ((uint32_t)f2bf(x.y - bf2f(h1)) << 16);
            int bo = m * 128 + ((l5 * 4) ^ ((m & 7) << 4));   // byte offset in 128B row
            *(uint32_t*)((char*)Ahi + bo) = hp;
            *(uint32_t*)((char*)Alo + bo) = lp;
        }
        __syncthreads();

        // ---- MFMA: wave w -> m-groups {2w, 2w+1}; 4-term split ----
        const int row0 = w * 32 + (lane & 15);
        const int sw   = (lane & 7) << 4;
        #pragma unroll
        for (int kk = 0; kk < 2; ++kk) {
            int colb = kk * 64 + ((lane >> 4) << 4);
            int o0 = row0 * 128 + (colb ^ sw);
            int o1 = o0 + 16 * 128;
            bfrag8 ah0 = *(const bfrag8*)((const char*)Ahi + o0);
            bfrag8 al0 = *(const bfrag8*)((const char*)Alo + o0);
            bfrag8 ah1 = *(const bfrag8*)((const char*)Ahi + o1);
            bfrag8 al1 = *(const bfrag8*)((const char*)Alo + o1);
            #pragma unroll
            for (int t = 0; t < 8; ++t) {
                bfrag8 wh = *(const bfrag8*)&Wc[0][(((t * 2 + kk) * 64 + lane) << 3)];
                bfrag8 wl = *(const bfrag8*)&Wc[1][(((t * 2 + kk) * 64 + lane) << 3)];
                acc[0][t] = __builtin_amdgcn_mfma_f32_16x16x32_bf16(ah0, wh, acc[0][t], 0, 0, 0);
                acc[0][t] = __builtin_amdgcn_mfma_f32_16x16x32_bf16(ah0, wl, acc[0][t], 0, 0, 0);
                acc[0][t] = __builtin_amdgcn_mfma_f32_16x16x32_bf16(al0, wh, acc[0][t], 0, 0, 0);
                acc[0][t] = __builtin_amdgcn_mfma_f32_16x16x32_bf16(al0, wl, acc[0][t], 0, 0, 0);
                acc[1][t] = __builtin_amdgcn_mfma_f32_16x16x32_bf16(ah1, wh, acc[1][t], 0, 0, 0);
                acc[1][t] = __builtin_amdgcn_mfma_f32_16x16x32_bf16(ah1, wl, acc[1][t], 0, 0, 0);
                acc[1][t] = __builtin_amdgcn_mfma_f32_16x16x32_bf16(al1, wh, acc[1][t], 0, 0, 0);
                acc[1][t] = __builtin_amdgcn_mfma_f32_16x16x32_bf16(al1, wl, acc[1][t], 0, 0, 0);
            }
        }
    }

    // ---- epilogue: rows<100 -> E; row 100 -> Q; row 101 -> P + b_cat ----
    float* Eg = E + (size_t)g * (CATC * NCOND);
    const int colL = lane & 15;
    const int quad = lane >> 4;
    #pragma unroll
    for (int t = 0; t < 8; ++t) {
        int c = t * 16 + colL;
        #pragma unroll
        for (int gi = 0; gi < 2; ++gi) {
            int mbase = (2 * w + gi) * 16 + quad * 4;
            #pragma unroll
            for (int r = 0; r < 4; ++r) {
                int m = mbase + r;
                float val = acc[gi][t][r];
                if (m < CATC)            Eg[m * NCOND + c] = val;
                else if (m == CATC)      Q[g * NCOND + c] = val;
                else if (m == CATC + 1)  P[g * NCOND + c] = val + b_cat[g * NCOND + c];
            }
        }
    }
}

// ---------------------------------------------------------------------------
// fused_out: per (sample, c-half). cat[g][c] = sigmoid(alpha*E + beta*Q + P)
// gathered from the L2-hot E table -> LDS T[c_loc][g] (pad 108: 432B rows,
// 16B-aligned, bank-offset 12/row) -> phase-2 cat reads are single
// conflict-free ds_read_b128 per thread. Output loops split into uniform
// num-region / cat-region passes. All global IO float4.
// ---------------------------------------------------------------------------
#define TPAD 108
__global__ __launch_bounds__(256)
void fused_out_kernel(const int* __restrict__ x_cat,
                      const float* __restrict__ x_num,
                      const float* __restrict__ Wt,   // [c][j]
                      const float* __restrict__ Bt,   // [c][j]
                      const float* __restrict__ Q,
                      const float* __restrict__ P,
                      const float2* __restrict__ S,
                      const float* __restrict__ E,
                      float* __restrict__ out)
{
    const int b   = blockIdx.x;
    const int h   = blockIdx.y;       // c-half: 0 or 1
    const int tid = threadIdx.x;
    __shared__ __align__(16) float T[64 * TPAD];   // [c_loc][g], 27.6 KB
    __shared__ float xr[NNUM];
    __shared__ float al[NCAT], be[NCAT];
    __shared__ int   ei[NCAT];

    if (tid < NNUM) xr[tid] = x_num[b * NNUM + tid];
    if (tid < NCAT) {
        int idx = x_cat[(size_t)b * NCAT + tid];
        ei[tid] = idx;
        float2 s2 = S[tid * CATC + idx];
        al[tid] = s2.x;
        be[tid] = s2.y;
    }
    __syncthreads();

    const float4* E4 = (const float4*)E;
    const float4* Q4 = (const float4*)Q;
    const float4* P4 = (const float4*)P;
    #pragma unroll
    for (int it = 0; it < 7; ++it) {
        int i4 = it * 256 + tid;                  // 0..1599 float4s of this half
        if (i4 < NCAT * 16) {
            int g    = i4 >> 4;
            int c4   = i4 & 15;
            int col4 = h * 16 + c4;
            float4 e = E4[(size_t)(g * CATC + ei[g]) * 32 + col4];
            float4 q = Q4[g * 32 + col4];
            float4 p = P4[g * 32 + col4];
            float a = al[g], bb = be[g];
            int cl = c4 * 4;                      // local c = c4*4 + e
            T[(cl    ) * TPAD + g] = sigmoidf_(fmaf(a, e.x, fmaf(bb, q.x, p.x)));
            T[(cl + 1) * TPAD + g] = sigmoidf_(fmaf(a, e.y, fmaf(bb, q.y, p.y)));
            T[(cl + 2) * TPAD + g] = sigmoidf_(fmaf(a, e.z, fmaf(bb, q.z, p.z)));
            T[(cl + 3) * TPAD + g] = sigmoidf_(fmaf(a, e.w, fmaf(bb, q.w, p.w)));
        }
    }
    __syncthreads();

    float4* outb = (float4*)(out + (size_t)b * (NCOND * 200)) + h * 3200;
    const float4* Wt4 = (const float4*)Wt;
    const float4* Bt4 = (const float4*)Bt;

    // ---- num region: 64 c-rows x 25 float4, uniform waves ----
    #pragma unroll
    for (int it = 0; it < 7; ++it) {
        int o4 = it * 256 + tid;                  // 0..1599
        if (o4 < 64 * 25) {
            int c_loc = o4 / 25;
            int j4    = o4 - c_loc * 25;
            int c     = h * 64 + c_loc;
            float4 wv = Wt4[c * 25 + j4];
            float4 bv = Bt4[c * 25 + j4];
            int j = j4 * 4;
            float4 v;
            v.x = sigmoidf_(fmaf(xr[j],     wv.x, bv.x));
            v.y = sigmoidf_(fmaf(xr[j + 1], wv.y, bv.y));
            v.z = sigmoidf_(fmaf(xr[j + 2], wv.z, bv.z));
            v.w = sigmoidf_(fmaf(xr[j + 3], wv.w, bv.w));
            outb[c_loc * 50 + j4] = v;
        }
    }
    // ---- cat region: 64 c-rows x 25 float4, one b128 LDS read each ----
    #pragma unroll
    for (int it = 0; it < 7; ++it) {
        int o4 = it * 256 + tid;                  // 0..1599
        if (o4 < 64 * 25) {
            int c_loc = o4 / 25;
            int g4    = o4 - c_loc * 25;
            float4 v = *(const float4*)&T[c_loc * TPAD + g4 * 4];
            outb[c_loc * 50 + 25 + g4] = v;
        }
    }
}

extern "C" void kernel_launch(void* const* d_in, const int* in_sizes, int n_in,
                              void* d_out, int out_size, void* d_ws, size_t ws_size,
                              hipStream_t stream)
{
    const float* x_num  = (const float*)d_in[0];
    const int*   x_cat  = (const int*)  d_in[1];
    const float* W_num  = (const float*)d_in[2];
    const float* b_num  = (const float*)d_in[3];
    const float* emb    = (const float*)d_in[4];
    const float* gn_w   = (const float*)d_in[5];
    const float* gn_b   = (const float*)d_in[6];
    const float* W_cat  = (const float*)d_in[7];
    const float* b_cat  = (const float*)d_in[8];
    float* out = (float*)d_out;

    const int B = in_sizes[0] / NNUM;                 // 4096

    // ws layout (~5.5 MB)
    float*  Wt = (float*)d_ws;                        // 12800
    float*  Bt = Wt + NCOND * NNUM;                   // 12800
    float*  Qb = Bt + NCOND * NNUM;                   // 12800
    float*  Pb = Qb + NCAT * NCOND;                   // 12800
    float2* Sb = (float2*)(Pb + NCAT * NCOND);        // 10000 float2
    float*  Eb = (float*)(Sb + NCAT * CATC);          // 1,280,000 floats

    prep_all<<<NCAT + 50, 256, 0, stream>>>(emb, W_cat, gn_w, gn_b, b_cat,
                                            W_num, b_num, Eb, Qb, Pb, Sb, Wt, Bt);
    fused_out_kernel<<<dim3(B, 2), 256, 0, stream>>>(x_cat, x_num, Wt, Bt, Qb, Pb, Sb, Eb, out);
}

// Round 7
// 525.100 us; speedup vs baseline: 1.0460x; 1.0460x over previous
//
#include <hip/hip_runtime.h>
#include <cstdint>

#define NNUM 100
#define NCAT 100
#define CATC 100
#define NCOND 128
#define GN_EPS 1e-5f

typedef __attribute__((ext_vector_type(8))) short bfrag8;   // 8 bf16 = 4 VGPRs
typedef __attribute__((ext_vector_type(4))) float accf4;    // 4 fp32 acc

__device__ __forceinline__ float sigmoidf_(float x) {
    // fast sigmoid: v_exp + v_rcp (1 ULP), plenty within absmax tolerance
    return __builtin_amdgcn_rcpf(1.0f + __expf(-x));
}

__device__ __forceinline__ ushort f2bf(float f) {
    uint32_t u = __builtin_bit_cast(uint32_t, f);
    u += 0x7fffu + ((u >> 16) & 1u);   // round-to-nearest-even
    return (ushort)(u >> 16);
}
__device__ __forceinline__ float bf2f(ushort h) {
    return __builtin_bit_cast(float, (uint32_t)h << 16);
}

// ---------------------------------------------------------------------------
// prep_misc: ONE launch, all-independent precomputation, zero LDS.
//  blocks 0..99    (g): W_cat[g] (RAW fp32) -> split-bf16 hi/lo planes in
//                       MFMA B-fragment order (Wf), coalesced 16B writes.
//       Wf[g*32768 + ((t*4+kk)*2 + plane)*512 + lane*8 + j]
//       fragment (t,kk): c = t*16 + (lane&15), k = kk*32 + (lane>>4)*8 + j.
//  blocks 100..149:     transpose W_num/b_num (100x128 -> 128x100) -> Wt/Bt.
//  blocks 150..2649:    row stats S[r] = (rs, -mean*rs), 4 rows/block.
// ---------------------------------------------------------------------------
__global__ __launch_bounds__(256)
void prep_misc(const float* __restrict__ emb_table,
               const float* __restrict__ W_cat,
               const float* __restrict__ W_num,
               const float* __restrict__ b_num,
               ushort* __restrict__ Wf,
               float2* __restrict__ S,
               float* __restrict__ Wt, float* __restrict__ Bt)
{
    const int bid  = blockIdx.x;
    const int tid  = threadIdx.x;
    const int lane = tid & 63;
    const int w    = tid >> 6;

    if (bid < NCAT) {
        // ---- Wf conversion (raw W_cat) ----
        const int g = bid;
        const float* Wg = W_cat + ((size_t)g << 14);
        ushort* Wfg = Wf + ((size_t)g << 15);
        #pragma unroll
        for (int i = 0; i < 8; ++i) {
            int p  = w * 8 + i;           // 0..31 (t,kk) pairs
            int t  = p >> 2, kk = p & 3;
            int c  = t * 16 + (lane & 15);
            int kb = kk * 32 + ((lane >> 4) << 3);
            ushort hi[8], lo[8];
            #pragma unroll
            for (int j = 0; j < 8; ++j) {
                float v = Wg[(kb + j) * NCOND + c];
                ushort h = f2bf(v);
                hi[j] = h;
                lo[j] = f2bf(v - bf2f(h));
            }
            int off = ((t * 4 + kk) * 2) * 512 + lane * 8;
            *(bfrag8*)(Wfg + off)       = *(const bfrag8*)hi;
            *(bfrag8*)(Wfg + off + 512) = *(const bfrag8*)lo;
        }
    } else if (bid < NCAT + 50) {
        // ---- transpose W_num/b_num ----
        int idx = (bid - NCAT) * 256 + tid;
        if (idx < NCOND * NNUM) {
            int c = idx / NNUM, j = idx - c * NNUM;
            Wt[idx] = W_num[j * NCOND + c];
            Bt[idx] = b_num[j * NCOND + c];
        }
    } else {
        // ---- row stats: 4 rows per block (one per wave) ----
        int r = (bid - NCAT - 50) * 4 + w;
        if (r < NCAT * CATC) {
            const float2* row = (const float2*)(emb_table + ((size_t)r << 7));
            float2 v = row[lane];
            float s  = v.x + v.y;
            float ss = v.x * v.x + v.y * v.y;
            #pragma unroll
            for (int off = 32; off > 0; off >>= 1) {
                s  += __shfl_xor(s,  off, 64);
                ss += __shfl_xor(ss, off, 64);
            }
            float mean = s * 0.0078125f;
            float var  = fmaf(-mean, mean, ss * 0.0078125f);
            float rs   = rsqrtf(var + GN_EPS);
            if (lane == 0) S[r] = make_float2(rs, -mean * rs);
        }
    }
}

// ---------------------------------------------------------------------------
// prep_E: E[g][cat][o] = (emb_row(g,cat)*gn_w[g]) @ W_cat[g], 4-term
// split-bf16 MFMA (~fp32 accurate). Pad rows of the 128-row A tile are free
// matvecs: row 100 = gn_w -> Q[g][o]; row 101 = gn_b -> P[g][o] (+b_cat).
// Grid (100, 2): block (g,h) computes c-columns h*64..h*64+63 using its Wf
// half; A staged wave-locally (no barrier), W frags from global Wf (L2-hot).
// ---------------------------------------------------------------------------
__global__ __launch_bounds__(256, 2)
void prep_E_kernel(const float* __restrict__ emb_table,
                   const float* __restrict__ gn_w,
                   const float* __restrict__ gn_b,
                   const float* __restrict__ b_cat,
                   const ushort* __restrict__ Wf,
                   float* __restrict__ E, float* __restrict__ Q, float* __restrict__ P)
{
    const int g    = blockIdx.x;
    const int h    = blockIdx.y;      // c-half
    const int tid  = threadIdx.x;
    const int lane = tid & 63;
    const int w    = tid >> 6;

    __shared__ __align__(16) ushort Ahi[128 * 128];   // [m][k] swizzled, 32 KB
    __shared__ __align__(16) ushort Alo[128 * 128];   // 32 KB

    const int half = lane >> 5;
    const int l5   = lane & 31;       // owns k = 4*l5 .. 4*l5+3
    float4 gwv = *(const float4*)(gn_w + g * NCOND + l5 * 4);
    float4 gbv = *(const float4*)(gn_b + g * NCOND + l5 * 4);

    #pragma unroll 8
    for (int it = 0; it < 16; ++it) {
        int r = it * 2 + half;
        int m = w * 32 + r;
        float4 x;
        if (m < CATC) {
            const float4* row = (const float4*)(emb_table + ((size_t)(g * CATC + m) << 7));
            float4 v = row[l5];
            x.x = v.x * gwv.x; x.y = v.y * gwv.y;
            x.z = v.z * gwv.z; x.w = v.w * gwv.w;
        } else if (m == CATC)     x = gwv;          // -> Q
        else if (m == CATC + 1)   x = gbv;          // -> P part
        else                      x = make_float4(0.f, 0.f, 0.f, 0.f);
        ushort h0 = f2bf(x.x), h1 = f2bf(x.y), h2 = f2bf(x.z), h3 = f2bf(x.w);
        uint2 hp = { (uint32_t)h0 | ((uint32_t)h1 << 16),
                     (uint32_t)h2 | ((uint32_t)h3 << 16) };
        uint2 lp = { (uint32_t)f2bf(x.x - bf2f(h0)) | ((uint32_t)f2bf(x.y - bf2f(h1)) << 16),
                     (uint32_t)f2bf(x.z - bf2f(h2)) | ((uint32_t)f2bf(x.w - bf2f(h3)) << 16) };
        int bo = m * 256 + ((l5 * 8) ^ ((m & 7) << 4));   // swizzled byte offset
        *(uint2*)((char*)Ahi + bo) = hp;
        *(uint2*)((char*)Alo + bo) = lp;
    }
    // wave-local producer->consumer: all ds_writes are this wave's own rows
    asm volatile("s_waitcnt lgkmcnt(0)" ::: "memory");

    accf4 acc[2][4];
    #pragma unroll
    for (int gi = 0; gi < 2; ++gi)
        #pragma unroll
        for (int t = 0; t < 4; ++t)
            acc[gi][t] = (accf4){0.f, 0.f, 0.f, 0.f};

    const ushort* Wfg = Wf + ((size_t)g << 15);
    const int row0 = w * 32 + (lane & 15);          // group 2w
    const int sw   = (lane & 7) << 4;

    #pragma unroll
    for (int kk = 0; kk < 4; ++kk) {
        int colb = kk * 64 + ((lane >> 4) << 4);
        int o0 = row0 * 256 + (colb ^ sw);
        int o1 = o0 + 16 * 256;                      // group 2w+1
        bfrag8 ah0 = *(const bfrag8*)((const char*)Ahi + o0);
        bfrag8 al0 = *(const bfrag8*)((const char*)Alo + o0);
        bfrag8 ah1 = *(const bfrag8*)((const char*)Ahi + o1);
        bfrag8 al1 = *(const bfrag8*)((const char*)Alo + o1);
        const ushort* wbase = Wfg + kk * 1024 + lane * 8;
        #pragma unroll
        for (int tt = 0; tt < 4; ++tt) {
            int t = h * 4 + tt;
            bfrag8 wh = *(const bfrag8*)(wbase + t * 4096);
            bfrag8 wl = *(const bfrag8*)(wbase + t * 4096 + 512);
            acc[0][tt] = __builtin_amdgcn_mfma_f32_16x16x32_bf16(ah0, wh, acc[0][tt], 0, 0, 0);
            acc[0][tt] = __builtin_amdgcn_mfma_f32_16x16x32_bf16(ah0, wl, acc[0][tt], 0, 0, 0);
            acc[0][tt] = __builtin_amdgcn_mfma_f32_16x16x32_bf16(al0, wh, acc[0][tt], 0, 0, 0);
            acc[0][tt] = __builtin_amdgcn_mfma_f32_16x16x32_bf16(al0, wl, acc[0][tt], 0, 0, 0);
            acc[1][tt] = __builtin_amdgcn_mfma_f32_16x16x32_bf16(ah1, wh, acc[1][tt], 0, 0, 0);
            acc[1][tt] = __builtin_amdgcn_mfma_f32_16x16x32_bf16(ah1, wl, acc[1][tt], 0, 0, 0);
            acc[1][tt] = __builtin_amdgcn_mfma_f32_16x16x32_bf16(al1, wh, acc[1][tt], 0, 0, 0);
            acc[1][tt] = __builtin_amdgcn_mfma_f32_16x16x32_bf16(al1, wl, acc[1][tt], 0, 0, 0);
        }
    }

    // ---- epilogue: rows<100 -> E; row 100 -> Q; row 101 -> P + b_cat ----
    float* Eg = E + (size_t)g * (CATC * NCOND);
    const int colL = lane & 15;
    const int quad = lane >> 4;
    #pragma unroll
    for (int tt = 0; tt < 4; ++tt) {
        int c = (h * 4 + tt) * 16 + colL;
        #pragma unroll
        for (int gi = 0; gi < 2; ++gi) {
            int mbase = (2 * w + gi) * 16 + quad * 4;
            #pragma unroll
            for (int r = 0; r < 4; ++r) {
                int m = mbase + r;
                float val = acc[gi][tt][r];
                if (m < CATC)            Eg[m * NCOND + c] = val;
                else if (m == CATC)      Q[g * NCOND + c] = val;
                else if (m == CATC + 1)  P[g * NCOND + c] = val + b_cat[g * NCOND + c];
            }
        }
    }
}

// ---------------------------------------------------------------------------
// fused_out: per (sample, c-half). cat[g][c] = sigmoid(alpha*E + beta*Q + P)
// gathered from the L2-hot E table -> LDS T[c_loc][g] (pad 108) -> phase-2
// cat reads are single conflict-free ds_read_b128 per thread. Output loops
// split into uniform num-region / cat-region passes. All global IO float4.
// ---------------------------------------------------------------------------
#define TPAD 108
__global__ __launch_bounds__(256)
void fused_out_kernel(const int* __restrict__ x_cat,
                      const float* __restrict__ x_num,
                      const float* __restrict__ Wt,   // [c][j]
                      const float* __restrict__ Bt,   // [c][j]
                      const float* __restrict__ Q,
                      const float* __restrict__ P,
                      const float2* __restrict__ S,
                      const float* __restrict__ E,
                      float* __restrict__ out)
{
    const int b   = blockIdx.x;
    const int h   = blockIdx.y;       // c-half: 0 or 1
    const int tid = threadIdx.x;
    __shared__ __align__(16) float T[64 * TPAD];   // [c_loc][g], 27.6 KB
    __shared__ float xr[NNUM];
    __shared__ float al[NCAT], be[NCAT];
    __shared__ int   ei[NCAT];

    if (tid < NNUM) xr[tid] = x_num[b * NNUM + tid];
    if (tid < NCAT) {
        int idx = x_cat[(size_t)b * NCAT + tid];
        ei[tid] = idx;
        float2 s2 = S[tid * CATC + idx];
        al[tid] = s2.x;
        be[tid] = s2.y;
    }
    __syncthreads();

    const float4* E4 = (const float4*)E;
    const float4* Q4 = (const float4*)Q;
    const float4* P4 = (const float4*)P;
    #pragma unroll
    for (int it = 0; it < 7; ++it) {
        int i4 = it * 256 + tid;                  // 0..1599 float4s of this half
        if (i4 < NCAT * 16) {
            int g    = i4 >> 4;
            int c4   = i4 & 15;
            int col4 = h * 16 + c4;
            float4 e = E4[(size_t)(g * CATC + ei[g]) * 32 + col4];
            float4 q = Q4[g * 32 + col4];
            float4 p = P4[g * 32 + col4];
            float a = al[g], bb = be[g];
            int cl = c4 * 4;                      // local c = c4*4 + e
            T[(cl    ) * TPAD + g] = sigmoidf_(fmaf(a, e.x, fmaf(bb, q.x, p.x)));
            T[(cl + 1) * TPAD + g] = sigmoidf_(fmaf(a, e.y, fmaf(bb, q.y, p.y)));
            T[(cl + 2) * TPAD + g] = sigmoidf_(fmaf(a, e.z, fmaf(bb, q.z, p.z)));
            T[(cl + 3) * TPAD + g] = sigmoidf_(fmaf(a, e.w, fmaf(bb, q.w, p.w)));
        }
    }
    __syncthreads();

    float4* outb = (float4*)(out + (size_t)b * (NCOND * 200)) + h * 3200;
    const float4* Wt4 = (const float4*)Wt;
    const float4* Bt4 = (const float4*)Bt;

    // ---- num region: 64 c-rows x 25 float4, uniform waves ----
    #pragma unroll
    for (int it = 0; it < 7; ++it) {
        int o4 = it * 256 + tid;                  // 0..1599
        if (o4 < 64 * 25) {
            int c_loc = o4 / 25;
            int j4    = o4 - c_loc * 25;
            int c     = h * 64 + c_loc;
            float4 wv = Wt4[c * 25 + j4];
            float4 bv = Bt4[c * 25 + j4];
            int j = j4 * 4;
            float4 v;
            v.x = sigmoidf_(fmaf(xr[j],     wv.x, bv.x));
            v.y = sigmoidf_(fmaf(xr[j + 1], wv.y, bv.y));
            v.z = sigmoidf_(fmaf(xr[j + 2], wv.z, bv.z));
            v.w = sigmoidf_(fmaf(xr[j + 3], wv.w, bv.w));
            outb[c_loc * 50 + j4] = v;
        }
    }
    // ---- cat region: 64 c-rows x 25 float4, one b128 LDS read each ----
    #pragma unroll
    for (int it = 0; it < 7; ++it) {
        int o4 = it * 256 + tid;                  // 0..1599
        if (o4 < 64 * 25) {
            int c_loc = o4 / 25;
            int g4    = o4 - c_loc * 25;
            float4 v = *(const float4*)&T[c_loc * TPAD + g4 * 4];
            outb[c_loc * 50 + 25 + g4] = v;
        }
    }
}

extern "C" void kernel_launch(void* const* d_in, const int* in_sizes, int n_in,
                              void* d_out, int out_size, void* d_ws, size_t ws_size,
                              hipStream_t stream)
{
    const float* x_num  = (const float*)d_in[0];
    const int*   x_cat  = (const int*)  d_in[1];
    const float* W_num  = (const float*)d_in[2];
    const float* b_num  = (const float*)d_in[3];
    const float* emb    = (const float*)d_in[4];
    const float* gn_w   = (const float*)d_in[5];
    const float* gn_b   = (const float*)d_in[6];
    const float* W_cat  = (const float*)d_in[7];
    const float* b_cat  = (const float*)d_in[8];
    float* out = (float*)d_out;

    const int B = in_sizes[0] / NNUM;                 // 4096

    // ws layout (~12 MB)
    float*  Wt = (float*)d_ws;                        // 12800
    float*  Bt = Wt + NCOND * NNUM;                   // 12800
    float*  Qb = Bt + NCOND * NNUM;                   // 12800
    float*  Pb = Qb + NCAT * NCOND;                   // 12800
    float2* Sb = (float2*)(Pb + NCAT * NCOND);        // 10000 float2
    float*  Eb = (float*)(Sb + NCAT * CATC);          // 1,280,000 floats
    ushort* Wf = (ushort*)(Eb + NCAT * CATC * NCOND); // 3,276,800 ushort

    prep_misc<<<NCAT + 50 + (NCAT * CATC + 3) / 4, 256, 0, stream>>>(
        emb, W_cat, W_num, b_num, Wf, Sb, Wt, Bt);
    prep_E_kernel<<<dim3(NCAT, 2), 256, 0, stream>>>(
        emb, gn_w, gn_b, b_cat, Wf, Eb, Qb, Pb);
    fused_out_kernel<<<dim3(B, 2), 256, 0, stream>>>(
        x_cat, x_num, Wt, Bt, Qb, Pb, Sb, Eb, out);
}

// Round 8
// 501.613 us; speedup vs baseline: 1.0950x; 1.0468x over previous
//
#include <hip/hip_runtime.h>
#include <cstdint>

#define NNUM 100
#define NCAT 100
#define CATC 100
#define NCOND 128
#define GN_EPS 1e-5f

typedef __attribute__((ext_vector_type(8))) short bfrag8;   // 8 bf16 = 4 VGPRs
typedef __attribute__((ext_vector_type(4))) float accf4;    // 4 fp32 acc

__device__ __forceinline__ float sigmoidf_(float x) {
    // fast sigmoid: v_exp + v_rcp (1 ULP), within absmax tolerance
    return __builtin_amdgcn_rcpf(1.0f + __expf(-x));
}

__device__ __forceinline__ ushort f2bf(float f) {
    uint32_t u = __builtin_bit_cast(uint32_t, f);
    u += 0x7fffu + ((u >> 16) & 1u);   // round-to-nearest-even
    return (ushort)(u >> 16);
}
__device__ __forceinline__ float bf2f(ushort h) {
    return __builtin_bit_cast(float, (uint32_t)h << 16);
}

// ---------------------------------------------------------------------------
// prep_misc: ONE launch, all-independent precomputation, zero LDS.
//  blocks 0..99    (g): W_cat[g] (RAW fp32) -> split-bf16 hi/lo planes in
//                       MFMA B-fragment order (Wf), coalesced 16B writes.
//  blocks 100..149:     transpose W_num/b_num (100x128 -> 128x100) -> Wt/Bt.
//  blocks 150..2649:    row stats S[r] = (rs, -mean*rs), 4 rows/block.
// ---------------------------------------------------------------------------
__global__ __launch_bounds__(256)
void prep_misc(const float* __restrict__ emb_table,
               const float* __restrict__ W_cat,
               const float* __restrict__ W_num,
               const float* __restrict__ b_num,
               ushort* __restrict__ Wf,
               float2* __restrict__ S,
               float* __restrict__ Wt, float* __restrict__ Bt)
{
    const int bid  = blockIdx.x;
    const int tid  = threadIdx.x;
    const int lane = tid & 63;
    const int w    = tid >> 6;

    if (bid < NCAT) {
        // ---- Wf conversion (raw W_cat) ----
        const int g = bid;
        const float* Wg = W_cat + ((size_t)g << 14);
        ushort* Wfg = Wf + ((size_t)g << 15);
        #pragma unroll
        for (int i = 0; i < 8; ++i) {
            int p  = w * 8 + i;           // 0..31 (t,kk) pairs
            int t  = p >> 2, kk = p & 3;
            int c  = t * 16 + (lane & 15);
            int kb = kk * 32 + ((lane >> 4) << 3);
            ushort hi[8], lo[8];
            #pragma unroll
            for (int j = 0; j < 8; ++j) {
                float v = Wg[(kb + j) * NCOND + c];
                ushort h = f2bf(v);
                hi[j] = h;
                lo[j] = f2bf(v - bf2f(h));
            }
            int off = ((t * 4 + kk) * 2) * 512 + lane * 8;
            *(bfrag8*)(Wfg + off)       = *(const bfrag8*)hi;
            *(bfrag8*)(Wfg + off + 512) = *(const bfrag8*)lo;
        }
    } else if (bid < NCAT + 50) {
        // ---- transpose W_num/b_num ----
        int idx = (bid - NCAT) * 256 + tid;
        if (idx < NCOND * NNUM) {
            int c = idx / NNUM, j = idx - c * NNUM;
            Wt[idx] = W_num[j * NCOND + c];
            Bt[idx] = b_num[j * NCOND + c];
        }
    } else {
        // ---- row stats: 4 rows per block (one per wave) ----
        int r = (bid - NCAT - 50) * 4 + w;
        if (r < NCAT * CATC) {
            const float2* row = (const float2*)(emb_table + ((size_t)r << 7));
            float2 v = row[lane];
            float s  = v.x + v.y;
            float ss = v.x * v.x + v.y * v.y;
            #pragma unroll
            for (int off = 32; off > 0; off >>= 1) {
                s  += __shfl_xor(s,  off, 64);
                ss += __shfl_xor(ss, off, 64);
            }
            float mean = s * 0.0078125f;
            float var  = fmaf(-mean, mean, ss * 0.0078125f);
            float rs   = rsqrtf(var + GN_EPS);
            if (lane == 0) S[r] = make_float2(rs, -mean * rs);
        }
    }
}

// ---------------------------------------------------------------------------
// prep_E: E[g][cat][o] = (emb_row(g,cat)*gn_w[g]) @ W_cat[g], 4-term
// split-bf16 MFMA (~fp32 accurate). Pad rows of the 128-row A tile are free
// matvecs: row 100 = gn_w -> Q[g][o]; row 101 = gn_b -> P[g][o] (+b_cat).
// Grid (100, 2): block (g,h) computes c-columns h*64..h*64+63 using its Wf
// half; A staged wave-locally (no barrier), W frags from global Wf (L2-hot).
// ---------------------------------------------------------------------------
__global__ __launch_bounds__(256, 2)
void prep_E_kernel(const float* __restrict__ emb_table,
                   const float* __restrict__ gn_w,
                   const float* __restrict__ gn_b,
                   const float* __restrict__ b_cat,
                   const ushort* __restrict__ Wf,
                   float* __restrict__ E, float* __restrict__ Q, float* __restrict__ P)
{
    const int g    = blockIdx.x;
    const int h    = blockIdx.y;      // c-half
    const int tid  = threadIdx.x;
    const int lane = tid & 63;
    const int w    = tid >> 6;

    __shared__ __align__(16) ushort Ahi[128 * 128];   // [m][k] swizzled, 32 KB
    __shared__ __align__(16) ushort Alo[128 * 128];   // 32 KB

    const int half = lane >> 5;
    const int l5   = lane & 31;       // owns k = 4*l5 .. 4*l5+3
    float4 gwv = *(const float4*)(gn_w + g * NCOND + l5 * 4);
    float4 gbv = *(const float4*)(gn_b + g * NCOND + l5 * 4);

    #pragma unroll 8
    for (int it = 0; it < 16; ++it) {
        int r = it * 2 + half;
        int m = w * 32 + r;
        float4 x;
        if (m < CATC) {
            const float4* row = (const float4*)(emb_table + ((size_t)(g * CATC + m) << 7));
            float4 v = row[l5];
            x.x = v.x * gwv.x; x.y = v.y * gwv.y;
            x.z = v.z * gwv.z; x.w = v.w * gwv.w;
        } else if (m == CATC)     x = gwv;          // -> Q
        else if (m == CATC + 1)   x = gbv;          // -> P part
        else                      x = make_float4(0.f, 0.f, 0.f, 0.f);
        ushort h0 = f2bf(x.x), h1 = f2bf(x.y), h2 = f2bf(x.z), h3 = f2bf(x.w);
        uint2 hp = { (uint32_t)h0 | ((uint32_t)h1 << 16),
                     (uint32_t)h2 | ((uint32_t)h3 << 16) };
        uint2 lp = { (uint32_t)f2bf(x.x - bf2f(h0)) | ((uint32_t)f2bf(x.y - bf2f(h1)) << 16),
                     (uint32_t)f2bf(x.z - bf2f(h2)) | ((uint32_t)f2bf(x.w - bf2f(h3)) << 16) };
        int bo = m * 256 + ((l5 * 8) ^ ((m & 7) << 4));   // swizzled byte offset
        *(uint2*)((char*)Ahi + bo) = hp;
        *(uint2*)((char*)Alo + bo) = lp;
    }
    // wave-local producer->consumer: all ds_writes are this wave's own rows
    asm volatile("s_waitcnt lgkmcnt(0)" ::: "memory");

    accf4 acc[2][4];
    #pragma unroll
    for (int gi = 0; gi < 2; ++gi)
        #pragma unroll
        for (int t = 0; t < 4; ++t)
            acc[gi][t] = (accf4){0.f, 0.f, 0.f, 0.f};

    const ushort* Wfg = Wf + ((size_t)g << 15);
    const int row0 = w * 32 + (lane & 15);          // group 2w
    const int sw   = (lane & 7) << 4;

    #pragma unroll
    for (int kk = 0; kk < 4; ++kk) {
        int colb = kk * 64 + ((lane >> 4) << 4);
        int o0 = row0 * 256 + (colb ^ sw);
        int o1 = o0 + 16 * 256;                      // group 2w+1
        bfrag8 ah0 = *(const bfrag8*)((const char*)Ahi + o0);
        bfrag8 al0 = *(const bfrag8*)((const char*)Alo + o0);
        bfrag8 ah1 = *(const bfrag8*)((const char*)Ahi + o1);
        bfrag8 al1 = *(const bfrag8*)((const char*)Alo + o1);
        const ushort* wbase = Wfg + kk * 1024 + lane * 8;
        #pragma unroll
        for (int tt = 0; tt < 4; ++tt) {
            int t = h * 4 + tt;
            bfrag8 wh = *(const bfrag8*)(wbase + t * 4096);
            bfrag8 wl = *(const bfrag8*)(wbase + t * 4096 + 512);
            acc[0][tt] = __builtin_amdgcn_mfma_f32_16x16x32_bf16(ah0, wh, acc[0][tt], 0, 0, 0);
            acc[0][tt] = __builtin_amdgcn_mfma_f32_16x16x32_bf16(ah0, wl, acc[0][tt], 0, 0, 0);
            acc[0][tt] = __builtin_amdgcn_mfma_f32_16x16x32_bf16(al0, wh, acc[0][tt], 0, 0, 0);
            acc[0][tt] = __builtin_amdgcn_mfma_f32_16x16x32_bf16(al0, wl, acc[0][tt], 0, 0, 0);
            acc[1][tt] = __builtin_amdgcn_mfma_f32_16x16x32_bf16(ah1, wh, acc[1][tt], 0, 0, 0);
            acc[1][tt] = __builtin_amdgcn_mfma_f32_16x16x32_bf16(ah1, wl, acc[1][tt], 0, 0, 0);
            acc[1][tt] = __builtin_amdgcn_mfma_f32_16x16x32_bf16(al1, wh, acc[1][tt], 0, 0, 0);
            acc[1][tt] = __builtin_amdgcn_mfma_f32_16x16x32_bf16(al1, wl, acc[1][tt], 0, 0, 0);
        }
    }

    // ---- epilogue: rows<100 -> E; row 100 -> Q; row 101 -> P + b_cat ----
    float* Eg = E + (size_t)g * (CATC * NCOND);
    const int colL = lane & 15;
    const int quad = lane >> 4;
    #pragma unroll
    for (int tt = 0; tt < 4; ++tt) {
        int c = (h * 4 + tt) * 16 + colL;
        #pragma unroll
        for (int gi = 0; gi < 2; ++gi) {
            int mbase = (2 * w + gi) * 16 + quad * 4;
            #pragma unroll
            for (int r = 0; r < 4; ++r) {
                int m = mbase + r;
                float val = acc[gi][tt][r];
                if (m < CATC)            Eg[m * NCOND + c] = val;
                else if (m == CATC)      Q[g * NCOND + c] = val;
                else if (m == CATC + 1)  P[g * NCOND + c] = val + b_cat[g * NCOND + c];
            }
        }
    }
}

// ---------------------------------------------------------------------------
// fused_out: per (sample, c-QUARTER). 32 c-rows per block -> LDS ~15.4 KB ->
// 8 blocks/CU (wave-capped, 100% occupancy). cat[g][c] = sigmoid(a*E+b*Q+P)
// gathered from L2-hot E -> T[c_loc][g] -> coalesced float4 writes; num
// branch fused. Uniform (branch-free) write loops. All global IO float4.
// ---------------------------------------------------------------------------
#define TPAD 108
__global__ __launch_bounds__(256)
void fused_out_kernel(const int* __restrict__ x_cat,
                      const float* __restrict__ x_num,
                      const float* __restrict__ Wt,   // [c][j]
                      const float* __restrict__ Bt,   // [c][j]
                      const float* __restrict__ Q,
                      const float* __restrict__ P,
                      const float2* __restrict__ S,
                      const float* __restrict__ E,
                      float* __restrict__ out)
{
    const int b   = blockIdx.x;
    const int q   = blockIdx.y;       // c-quarter: 0..3
    const int tid = threadIdx.x;
    __shared__ __align__(16) float T[32 * TPAD];   // [c_loc][g], 13.8 KB
    __shared__ float xr[NNUM];
    __shared__ float al[NCAT], be[NCAT];
    __shared__ int   ei[NCAT];

    if (tid < NNUM) xr[tid] = x_num[b * NNUM + tid];
    if (tid < NCAT) {
        int idx = x_cat[(size_t)b * NCAT + tid];
        ei[tid] = idx;
        float2 s2 = S[tid * CATC + idx];
        al[tid] = s2.x;
        be[tid] = s2.y;
    }
    __syncthreads();

    const float4* E4 = (const float4*)E;
    const float4* Q4 = (const float4*)Q;
    const float4* P4 = (const float4*)P;
    // phase 1: gather + sigmoid + transpose-store (800 float4 of this quarter)
    #pragma unroll
    for (int it = 0; it < 4; ++it) {
        int i4 = it * 256 + tid;                  // 0..799
        if (i4 < NCAT * 8) {
            int g    = i4 >> 3;
            int c4   = i4 & 7;
            int col4 = q * 8 + c4;
            float4 e = E4[(size_t)(g * CATC + ei[g]) * 32 + col4];
            float4 qq = Q4[g * 32 + col4];
            float4 p = P4[g * 32 + col4];
            float a = al[g], bb = be[g];
            int cl = c4 * 4;                      // local c = c4*4 + e
            T[(cl    ) * TPAD + g] = sigmoidf_(fmaf(a, e.x, fmaf(bb, qq.x, p.x)));
            T[(cl + 1) * TPAD + g] = sigmoidf_(fmaf(a, e.y, fmaf(bb, qq.y, p.y)));
            T[(cl + 2) * TPAD + g] = sigmoidf_(fmaf(a, e.z, fmaf(bb, qq.z, p.z)));
            T[(cl + 3) * TPAD + g] = sigmoidf_(fmaf(a, e.w, fmaf(bb, qq.w, p.w)));
        }
    }
    __syncthreads();

    float4* outb = (float4*)(out + (size_t)b * (NCOND * 200)) + q * 1600;
    const float4* Wt4 = (const float4*)Wt;
    const float4* Bt4 = (const float4*)Bt;

    // ---- num region: 32 c-rows x 25 float4, uniform waves ----
    #pragma unroll
    for (int it = 0; it < 4; ++it) {
        int o4 = it * 256 + tid;                  // 0..799
        if (o4 < 32 * 25) {
            int c_loc = o4 / 25;
            int j4    = o4 - c_loc * 25;
            int c     = q * 32 + c_loc;
            float4 wv = Wt4[c * 25 + j4];
            float4 bv = Bt4[c * 25 + j4];
            int j = j4 * 4;
            float4 v;
            v.x = sigmoidf_(fmaf(xr[j],     wv.x, bv.x));
            v.y = sigmoidf_(fmaf(xr[j + 1], wv.y, bv.y));
            v.z = sigmoidf_(fmaf(xr[j + 2], wv.z, bv.z));
            v.w = sigmoidf_(fmaf(xr[j + 3], wv.w, bv.w));
            outb[c_loc * 50 + j4] = v;
        }
    }
    // ---- cat region: 32 c-rows x 25 float4, one b128 LDS read each ----
    #pragma unroll
    for (int it = 0; it < 4; ++it) {
        int o4 = it * 256 + tid;                  // 0..799
        if (o4 < 32 * 25) {
            int c_loc = o4 / 25;
            int g4    = o4 - c_loc * 25;
            float4 v = *(const float4*)&T[c_loc * TPAD + g4 * 4];   // 432B rows: 16B-aligned
            outb[c_loc * 50 + 25 + g4] = v;
        }
    }
}

extern "C" void kernel_launch(void* const* d_in, const int* in_sizes, int n_in,
                              void* d_out, int out_size, void* d_ws, size_t ws_size,
                              hipStream_t stream)
{
    const float* x_num  = (const float*)d_in[0];
    const int*   x_cat  = (const int*)  d_in[1];
    const float* W_num  = (const float*)d_in[2];
    const float* b_num  = (const float*)d_in[3];
    const float* emb    = (const float*)d_in[4];
    const float* gn_w   = (const float*)d_in[5];
    const float* gn_b   = (const float*)d_in[6];
    const float* W_cat  = (const float*)d_in[7];
    const float* b_cat  = (const float*)d_in[8];
    float* out = (float*)d_out;

    const int B = in_sizes[0] / NNUM;                 // 4096

    // ws layout (~12 MB)
    float*  Wt = (float*)d_ws;                        // 12800
    float*  Bt = Wt + NCOND * NNUM;                   // 12800
    float*  Qb = Bt + NCOND * NNUM;                   // 12800
    float*  Pb = Qb + NCAT * NCOND;                   // 12800
    float2* Sb = (float2*)(Pb + NCAT * NCOND);        // 10000 float2
    float*  Eb = (float*)(Sb + NCAT * CATC);          // 1,280,000 floats
    ushort* Wf = (ushort*)(Eb + NCAT * CATC * NCOND); // 3,276,800 ushort

    prep_misc<<<NCAT + 50 + (NCAT * CATC + 3) / 4, 256, 0, stream>>>(
        emb, W_cat, W_num, b_num, Wf, Sb, Wt, Bt);
    prep_E_kernel<<<dim3(NCAT, 2), 256, 0, stream>>>(
        emb, gn_w, gn_b, b_cat, Wf, Eb, Qb, Pb);
    fused_out_kernel<<<dim3(B, 4), 256, 0, stream>>>(
        x_cat, x_num, Wt, Bt, Qb, Pb, Sb, Eb, out);
}